// Round 14
// baseline (209.645 us; speedup 1.0000x reference)
//
#include <hip/hip_runtime.h>

typedef __attribute__((ext_vector_type(4))) float f32x4;
typedef __attribute__((ext_vector_type(8))) short short8;
typedef __attribute__((ext_vector_type(8))) unsigned short u16x8;
typedef __attribute__((ext_vector_type(4))) unsigned short u16x4;
typedef __attribute__((ext_vector_type(2))) unsigned int u32x2;

#define D_MODEL 1024
#define NHEADS 16
#define T_SEQ 2048
#define M_TOT 4096   // B*T

__device__ __forceinline__ unsigned short f2bf(float f) {
    union { float f; unsigned int u; } v; v.f = f;
    return (unsigned short)((v.u + 0x7fffu + ((v.u >> 16) & 1u)) >> 16);
}
__device__ __forceinline__ float bf2f(unsigned short b) {
    union { unsigned int u; float f; } v; v.u = ((unsigned int)b) << 16;
    return v.f;
}
// packed f32x2 -> bf16x2 (low = src0, high = src1)
__device__ __forceinline__ unsigned int cvtpk_bf16(float lo, float hi) {
    unsigned int r;
    asm("v_cvt_pk_bf16_f32 %0, %1, %2" : "=v"(r) : "v"(lo), "v"(hi));
    return r;
}

// volatile asm load: issue point pinned (cannot be sunk/hoisted by the compiler)
#define GLD0(dst, addr) \
    asm volatile("global_load_dwordx4 %0, %1, off" : "=v"(dst) : "v"(addr) : "memory")
// wait all asm/glds loads done, and fence the scheduler (guide rule #18)
#define WAITV0() do { asm volatile("s_waitcnt vmcnt(0)" ::: "memory"); \
                      __builtin_amdgcn_sched_barrier(0); } while (0)
// raw barrier: drain LDS only (NOT vmcnt -> in-flight prefetch survives the barrier)
#define LBAR() do { asm volatile("s_waitcnt lgkmcnt(0)" ::: "memory"); \
                    __builtin_amdgcn_s_barrier(); \
                    __builtin_amdgcn_sched_barrier(0); } while (0)

// async global -> LDS, 16B per lane, LDS dest = wave-uniform base + lane*16
#define GLDS16(gp, lp) \
    __builtin_amdgcn_global_load_lds((const __attribute__((address_space(1))) void*)(gp), \
                                     (__attribute__((address_space(3))) void*)(lp), 16, 0, 0)

// ---------------- prep: convert x fp32->bf16  +  4x W transpose->bf16 (one launch) ----------------
__global__ __launch_bounds__(256) void prep_kernel(const float* __restrict__ X,
                                                   unsigned short* __restrict__ Xb,
                                                   const float* __restrict__ W0,
                                                   const float* __restrict__ W1,
                                                   const float* __restrict__ W2,
                                                   const float* __restrict__ W3,
                                                   unsigned short* __restrict__ Wt0) {
    __shared__ float tile[64][65];
    const int z = blockIdx.z;
    if (z >= 4) {
        // convert: 16 z-slices x 256 blocks x 256 thr x 4 floats = 4096*1024
        const int blk = (z - 4) * 256 + blockIdx.y * 16 + blockIdx.x;
        const int i = (blk * 256 + threadIdx.x) * 4;
        const float4 v = *(const float4*)(X + i);
        u16x4 r;
        r.x = f2bf(v.x); r.y = f2bf(v.y); r.z = f2bf(v.z); r.w = f2bf(v.w);
        *(u16x4*)(Xb + i) = r;
        return;
    }
    const float* W = (z == 0) ? W0 : (z == 1) ? W1 : (z == 2) ? W2 : W3;
    unsigned short* Wt = Wt0 + (size_t)z * D_MODEL * D_MODEL;
    const int n0 = blockIdx.x * 64, k0 = blockIdx.y * 64;
    for (int i = threadIdx.x; i < 4096; i += 256) {
        const int r = i >> 6, c = i & 63;
        tile[r][c] = W[(size_t)(k0 + r) * D_MODEL + n0 + c];
    }
    __syncthreads();
    for (int i = threadIdx.x; i < 4096; i += 256) {
        const int r = i >> 6, c = i & 63;  // r: n-local, c: k-local
        Wt[(size_t)(n0 + r) * D_MODEL + k0 + c] = f2bf(tile[c][r]);
    }
}

// ---------------- QKV GEMM: 128m x 64n blocks, 3 resident/CU, zero tail ----------------
// R14: dedicated QKV kernel. TN=64: LDS = 32KB(A,dbuf) + 16KB(B,dbuf) = 48KB ->
// 3 blocks/CU (vs 2 at TN=128); grid (32,16,3) = 1536 blocks = EXACTLY 2 rounds over
// 768 resident slots (the old 768-over-512 layout had a 256-block tail running at the
// degraded 1-block/CU rate, measured in R12). 4 waves each own 32 rows x all 64 cols
// (MI=2); all waves broadcast-read the same B rows from LDS (free). Same glds +
// pre-swizzled-source staging as R11 (conflict-free frag reads).
// Epilogues: z=0 Q(RoPE,*0.125), z=1 K(RoPE + fused kmax -> Ks[bh][64], one slot
// per 32-row wave), z=2 V(transposed).
__global__ __launch_bounds__(256) void qkv_kernel(
    const unsigned short* __restrict__ A,      // xb [4096][1024]
    const unsigned short* __restrict__ Bt0,    // wt [z][n][k]
    unsigned short* __restrict__ Out,          // Q,K,V contiguous (8MB each)
    const float* __restrict__ cosp,
    const float* __restrict__ sinp,
    float* __restrict__ Kmax)                  // [bh][64]
{
    __shared__ unsigned short sA[2][128 * 64];
    __shared__ unsigned short sB[2][64 * 64];

    const int tid = threadIdx.x;
    const int wid = tid >> 6;
    const int lane = tid & 63;
    const int quad = lane >> 4;
    const int l16 = lane & 15;
    const int m0 = blockIdx.x * 128, n0 = blockIdx.y * 64;
    const int z = blockIdx.z;
    const unsigned short* Bt = Bt0 + (size_t)z * D_MODEL * D_MODEL;
    const int r8 = lane >> 3;               // staging row within chunk (0..7)
    const int c8 = lane & 7;                // staging 16B slot (0..7)
    const int cswz = (c8 ^ r8) * 8;         // swizzled global u16 col offset
    const int rx = l16 & 7;                 // frag-read row XOR

    f32x4 acc[2][4] = {};

    auto STAGE = [&](int b, int k0) {
        for (int ch = wid; ch < 24; ch += 4) {   // 16 A-chunks + 8 B-chunks (8 rows each)
            if (ch < 16)
                GLDS16(A + (size_t)(m0 + ch * 8 + r8) * D_MODEL + k0 + cswz,
                       &sA[b][ch * 512]);
            else
                GLDS16(Bt + (size_t)(n0 + (ch - 16) * 8 + r8) * D_MODEL + k0 + cswz,
                       &sB[b][(ch - 16) * 512]);
        }
    };
    auto COMPUTE = [&](int b) {
        #pragma unroll
        for (int ks = 0; ks < 2; ++ks) {
            const int sx = ((ks * 4 + quad) ^ rx) * 8;
            short8 af[2], bf[4];
            #pragma unroll
            for (int i = 0; i < 2; ++i)
                af[i] = *(const short8*)&sA[b][(wid * 32 + i * 16 + l16) * 64 + sx];
            #pragma unroll
            for (int i = 0; i < 4; ++i)
                bf[i] = *(const short8*)&sB[b][(i * 16 + l16) * 64 + sx];
            #pragma unroll
            for (int mi = 0; mi < 2; ++mi)
                #pragma unroll
                for (int ni = 0; ni < 4; ++ni)
                    acc[mi][ni] = __builtin_amdgcn_mfma_f32_16x16x32_bf16(af[mi], bf[ni], acc[mi][ni], 0, 0, 0);
        }
    };

    STAGE(0, 0);
    WAITV0();
    LBAR();
    for (int kk = 0; kk < 16; ++kk) {
        if (kk + 1 < 16) STAGE((kk + 1) & 1, (kk + 1) * 64);
        COMPUTE(kk & 1);
        WAITV0();          // own glds drained (flew during COMPUTE)
        LBAR();
    }

    unsigned short* O = Out + (size_t)z * M_TOT * D_MODEL;
    const int h = n0 >> 6;                  // block's 64 cols = exactly one head
    if (z == 2) {
        // V: write transposed Vt[bh][d][t], packed u16x4 over 4 consecutive t
        #pragma unroll
        for (int mi = 0; mi < 2; ++mi) {
            const int mb = m0 + wid * 32 + mi * 16 + quad * 4;
            const int b = mb >> 11, t = mb & (T_SEQ - 1);
            #pragma unroll
            for (int ni = 0; ni < 4; ++ni) {
                const int d = ni * 16 + l16;
                u16x4 pk;
                #pragma unroll
                for (int r = 0; r < 4; ++r) pk[r] = f2bf(acc[mi][ni][r]);
                *(u16x4*)(O + ((size_t)(b * NHEADS + h) * 64 + d) * T_SEQ + t) = pk;
            }
        }
    } else {
        if (z == 1) {
            // fused kmax over this wave's 32 rows (one head, fp32 acc; RoPE is a rotation)
            float mx = 0.f;
            #pragma unroll
            for (int mi = 0; mi < 2; ++mi)
                #pragma unroll
                for (int r = 0; r < 4; ++r) {
                    float s = 0.f;
                    #pragma unroll
                    for (int ni = 0; ni < 4; ++ni) s += acc[mi][ni][r] * acc[mi][ni][r];
                    s += __shfl_xor(s, 1); s += __shfl_xor(s, 2);
                    s += __shfl_xor(s, 4); s += __shfl_xor(s, 8);
                    mx = fmaxf(mx, s);
                }
            mx = fmaxf(mx, __shfl_xor(mx, 16));
            mx = fmaxf(mx, __shfl_xor(mx, 32));
            if (lane == 0) {
                const int b = m0 >> 11;
                const int slot = ((m0 + wid * 32) >> 5) & 63;
                Kmax[(size_t)(b * NHEADS + h) * 64 + slot] = __builtin_sqrtf(mx);
            }
        }
        const float qs = (z == 0) ? 0.125f : 1.0f;   // fold 1/sqrt(64) into Q (exact in bf16)
        #pragma unroll
        for (int mi = 0; mi < 2; ++mi) {
            #pragma unroll
            for (int r = 0; r < 4; ++r) {
                const int m = m0 + wid * 32 + mi * 16 + quad * 4 + r;
                const int b = m >> 11, t = m & (T_SEQ - 1);
                const size_t rowoff = ((size_t)(b * NHEADS + h) * T_SEQ + t) * 64;
                #pragma unroll
                for (int ni = 0; ni < 2; ++ni) {
                    const int d = ni * 16 + l16;           // 0..31
                    const float c = cosp[t * 32 + d], s = sinp[t * 32 + d];
                    const float x1 = acc[mi][ni][r], x2 = acc[mi][ni + 2][r];
                    O[rowoff + d]      = f2bf((x1 * c - x2 * s) * qs);
                    O[rowoff + d + 32] = f2bf((x1 * s + x2 * c) * qs);
                }
            }
        }
    }
}

// ---------------- out-proj GEMM (unchanged R13 structure: MI=2, 48KB, 3 resident) ----------------
#define TN_G 128
#define BK_G 64

template<int MI>
__global__ __launch_bounds__(256) void gemm_kernel(
    const unsigned short* __restrict__ A,
    const unsigned short* __restrict__ Bt,
    float* __restrict__ C)
{
    constexpr int TMc = MI * 32;
    constexpr int NCHA = TMc / 8;
    constexpr int NCHB = TN_G / 8;
    __shared__ unsigned short sA[2][TMc * 64];
    __shared__ unsigned short sB[2][TN_G * 64];

    const int tid = threadIdx.x;
    const int wid = tid >> 6;
    const int lane = tid & 63;
    const int quad = lane >> 4;
    const int l16 = lane & 15;
    const int wm = wid >> 1, wn = wid & 1;
    const int m0 = blockIdx.x * TMc, n0 = blockIdx.y * TN_G;
    const int r8 = lane >> 3;
    const int c8 = lane & 7;
    const int cswz = (c8 ^ r8) * 8;
    const int rx = l16 & 7;

    f32x4 acc[MI][4] = {};

    auto STAGE = [&](int b, int k0) {
        for (int ch = wid; ch < NCHA + NCHB; ch += 4) {
            if (ch < NCHA)
                GLDS16(A + (size_t)(m0 + ch * 8 + r8) * D_MODEL + k0 + cswz,
                       &sA[b][ch * 512]);
            else
                GLDS16(Bt + (size_t)(n0 + (ch - NCHA) * 8 + r8) * D_MODEL + k0 + cswz,
                       &sB[b][(ch - NCHA) * 512]);
        }
    };
    auto COMPUTE = [&](int b) {
        #pragma unroll
        for (int ks = 0; ks < 2; ++ks) {
            const int sx = ((ks * 4 + quad) ^ rx) * 8;
            short8 af[MI], bf[4];
            #pragma unroll
            for (int i = 0; i < MI; ++i)
                af[i] = *(const short8*)&sA[b][(wm * (MI * 16) + i * 16 + l16) * 64 + sx];
            #pragma unroll
            for (int i = 0; i < 4; ++i)
                bf[i] = *(const short8*)&sB[b][(wn * 64 + i * 16 + l16) * 64 + sx];
            #pragma unroll
            for (int mi = 0; mi < MI; ++mi)
                #pragma unroll
                for (int ni = 0; ni < 4; ++ni)
                    acc[mi][ni] = __builtin_amdgcn_mfma_f32_16x16x32_bf16(af[mi], bf[ni], acc[mi][ni], 0, 0, 0);
        }
    };

    STAGE(0, 0);
    WAITV0();
    LBAR();
    for (int kk = 0; kk < D_MODEL / BK_G; ++kk) {
        if (kk + 1 < D_MODEL / BK_G) STAGE((kk + 1) & 1, (kk + 1) * BK_G);
        COMPUTE(kk & 1);
        WAITV0();
        LBAR();
    }

    #pragma unroll
    for (int mi = 0; mi < MI; ++mi) {
        const int mb = m0 + wm * (MI * 16) + mi * 16 + quad * 4;
        #pragma unroll
        for (int ni = 0; ni < 4; ++ni) {
            const int n = n0 + wn * 64 + ni * 16 + l16;
            #pragma unroll
            for (int r = 0; r < 4; ++r)
                C[(size_t)(mb + r) * D_MODEL + n] = acc[mi][ni][r];
        }
    }
}

// ---------------- flash attention (causal): SINGLE-PASS, Cauchy-Schwarz max bound ----------------
// m_hat = ||q_row|| * max_j ||k_j|| >= max s (softmax shift-invariant -> exact math).
// p = exp2(s*log2e - m_hat*log2e) <= ~1 structurally.
// R9/R13 structure: cooperative LDS staging, kv double buffer, one barrier/round,
// XOR-swizzled P, setprio, ones-MFMA denominator. Kseg now [bh][64].
#define LOG2E 1.44269504f

struct AttnSmem {
    union {
        unsigned short kv[2][4][4096];  // [buf][K0,V0,K1,V1][row*64 + swz-slot*8] = 65536 B
        float comb[4][64][40];          // 40960 B: half=1 partials (O 32 + lacA 4 + lacB 4)
    } u;
    unsigned short P[8][16 * 64];       // per-wave P tile, XOR-swizzled rows = 16384 B
};                                      // total 81920 B

__global__ __launch_bounds__(512, 2) void attn_kernel(
    const unsigned short* __restrict__ Q,    // [bh][t][64] bf16, RoPE'd, pre-scaled 0.125
    const unsigned short* __restrict__ Kg,   // [bh][t][64] bf16, RoPE'd
    const unsigned short* __restrict__ Vt,   // [bh][d][t]  bf16 (transposed)
    const float* __restrict__ Kseg,          // [bh][64] segment maxes of ||k||
    unsigned short* __restrict__ Z)          // [m][h*64+d] bf16
{
    __shared__ AttnSmem sm;

    const int tid = threadIdx.x;
    const int wid = tid >> 6;        // 0..7
    const int w4 = wid & 3;          // row-slice within q-tile
    const int half = wid >> 2;       // 0: even j, 1: odd j
    const int lane = tid & 63;
    const int quad = lane >> 4;
    const int l16 = lane & 15;
    const int srow = tid >> 3;       // staging row 0..63
    const int sslot = tid & 7;       // staging 16B slot
    const int wslot = sslot ^ (srow & 7);          // swizzled slot
    const int sxK = (quad ^ (l16 & 7)) << 3;       // kv frag-read swizzled elem offset
    const int ph8 = (l16 & 7) << 3;                // P row XOR (u16 units)

    // XCD-locality remap (bijective): flat%8 selects XCD; each XCD owns 4 whole bh.
    const int flat = blockIdx.x + 16 * blockIdx.y;     // 0..511
    const int xcd = flat & 7, idx = flat >> 3;         // idx 0..63
    const int bh = xcd * 4 + (idx & 3);                // 0..31
    const int x = idx >> 2;                            // 0..15

    const int qA = x, qB = 31 - x;       // paired q-tiles: 33 tiles/block, constant
    const int jend = 31 - x;             // kv tiles 0..jend cover both

    const unsigned short* Qp = Q + (size_t)bh * T_SEQ * 64;
    const unsigned short* Kp = Kg + (size_t)bh * T_SEQ * 64;
    const unsigned short* Vp = Vt + (size_t)bh * 64 * T_SEQ;

    // Q frags (B-operand in swapped QK): row = qt*64 + w4*16 + l16, k = ks*32 + quad*8
    short8 aqA[2], aqB[2];
    {
        const unsigned short* qr = Qp + (size_t)(qA * 64 + w4 * 16 + l16) * 64 + quad * 8;
        aqA[0] = *(const short8*)(qr);
        aqA[1] = *(const short8*)(qr + 32);
        qr = Qp + (size_t)(qB * 64 + w4 * 16 + l16) * 64 + quad * 8;
        aqB[0] = *(const short8*)(qr);
        aqB[1] = *(const short8*)(qr + 32);
    }

    // max bound: per-lane scalar for q-row l16 (swapped layout: lane = q-row)
    float kmx = 0.f;
    #pragma unroll
    for (int i = 0; i < 64; ++i) kmx = fmaxf(kmx, Kseg[bh * 64 + i]);

    float mQA, mQB;
    {
        float nqA = 0.f, nqB = 0.f;
        #pragma unroll
        for (int i = 0; i < 2; ++i)
            #pragma unroll
            for (int e = 0; e < 8; ++e) {
                const float fa = bf2f((unsigned short)aqA[i][e]);
                const float fb = bf2f((unsigned short)aqB[i][e]);
                nqA += fa * fa; nqB += fb * fb;
            }
        nqA += __shfl_xor(nqA, 16); nqA += __shfl_xor(nqA, 32);
        nqB += __shfl_xor(nqB, 16); nqB += __shfl_xor(nqB, 32);
        mQA = __builtin_sqrtf(nqA) * kmx * LOG2E;
        mQB = __builtin_sqrtf(nqB) * kmx * LOG2E;
    }

    // ones B-frag for the denominator MFMA (bf16 1.0 = 0x3F80)
    short8 bones;
    #pragma unroll
    for (int e = 0; e < 8; ++e) bones[e] = (short)0x3F80;

    auto tile_pack = [&](f32x4 (&s)[4], float mQ, bool msk, unsigned short* Pw) {
        if (msk) {
            #pragma unroll
            for (int nt = 0; nt < 4; ++nt)
                #pragma unroll
                for (int r = 0; r < 4; ++r)
                    if (nt * 16 + quad * 4 + r > w4 * 16 + l16) s[nt][r] = -1e30f;
        }
        #pragma unroll
        for (int nt = 0; nt < 4; ++nt) {
            const float p0 = __builtin_exp2f(s[nt][0] * LOG2E - mQ);
            const float p1 = __builtin_exp2f(s[nt][1] * LOG2E - mQ);
            const float p2 = __builtin_exp2f(s[nt][2] * LOG2E - mQ);
            const float p3 = __builtin_exp2f(s[nt][3] * LOG2E - mQ);
            const unsigned int w0 = cvtpk_bf16(p0, p1);
            const unsigned int w1 = cvtpk_bf16(p2, p3);
            *(u32x2*)&Pw[l16 * 64 + ((nt * 16 + quad * 4) ^ ph8)] = (u32x2){w0, w1};
        }
    };

    f32x4 oA[4] = {}, oB[4] = {};
    f32x4 lacA = {}, lacB = {};          // denominator accumulators (C-layout rows)
    unsigned short* Pw = &sm.P[wid][0];

    short8 stg[4];
    auto ISSUE = [&](int t) {   // 4 contiguous 16B loads per thread (pinned issue)
        const int j0 = 2 * t, j1 = j0 + 1;
        GLD0(stg[0], Kp + (size_t)j0 * 4096 + tid * 8);
        GLD0(stg[1], Vp + (size_t)srow * 2048 + j0 * 64 + sslot * 8);
        GLD0(stg[2], Kp + (size_t)j1 * 4096 + tid * 8);
        GLD0(stg[3], Vp + (size_t)srow * 2048 + j1 * 64 + sslot * 8);
    };
    auto WRITE = [&](int b) {   // swizzled LDS store of the staged 64B
        const int dst = srow * 64 + (wslot << 3);
        *(short8*)&sm.u.kv[b][0][dst] = stg[0];
        *(short8*)&sm.u.kv[b][1][dst] = stg[1];
        *(short8*)&sm.u.kv[b][2][dst] = stg[2];
        *(short8*)&sm.u.kv[b][3][dst] = stg[3];
    };

    auto COMPUTE = [&](int j, int b) {
        if (j > jend) return;            // last round: odd half may be inactive
        const bool doA = (j <= x);
        const unsigned short* sKb = &sm.u.kv[b][half * 2][0];
        const unsigned short* sVb = &sm.u.kv[b][half * 2 + 1][0];
        f32x4 sA[4] = {}, sB[4] = {};
        __builtin_amdgcn_s_setprio(1);
        #pragma unroll
        for (int nt = 0; nt < 4; ++nt) {
            const int rb = (nt * 16 + l16) * 64;
            const short8 k0 = *(const short8*)&sKb[rb + sxK];
            const short8 k1 = *(const short8*)&sKb[rb + (sxK ^ 32)];
            if (doA) {
                sA[nt] = __builtin_amdgcn_mfma_f32_16x16x32_bf16(k0, aqA[0], sA[nt], 0, 0, 0);
                sA[nt] = __builtin_amdgcn_mfma_f32_16x16x32_bf16(k1, aqA[1], sA[nt], 0, 0, 0);
            }
            sB[nt] = __builtin_amdgcn_mfma_f32_16x16x32_bf16(k0, aqB[0], sB[nt], 0, 0, 0);
            sB[nt] = __builtin_amdgcn_mfma_f32_16x16x32_bf16(k1, aqB[1], sB[nt], 0, 0, 0);
        }
        __builtin_amdgcn_s_setprio(0);
        short8 pfA0 = {}, pfA1 = {};
        if (doA) {
            tile_pack(sA, mQA, j == x, Pw);
            asm volatile("s_waitcnt lgkmcnt(0)" ::: "memory");
            pfA0 = *(const short8*)&Pw[l16 * 64 + ((quad * 8) ^ ph8)];
            pfA1 = *(const short8*)&Pw[l16 * 64 + ((32 + quad * 8) ^ ph8)];
        }
        tile_pack(sB, mQB, j == jend, Pw);
        asm volatile("s_waitcnt lgkmcnt(0)" ::: "memory");
        const short8 pfB0 = *(const short8*)&Pw[l16 * 64 + ((quad * 8) ^ ph8)];
        const short8 pfB1 = *(const short8*)&Pw[l16 * 64 + ((32 + quad * 8) ^ ph8)];
        __builtin_amdgcn_s_setprio(1);
        #pragma unroll
        for (int dt = 0; dt < 4; ++dt) {
            const int rb = (dt * 16 + l16) * 64;
            const short8 v0 = *(const short8*)&sVb[rb + sxK];
            const short8 v1 = *(const short8*)&sVb[rb + (sxK ^ 32)];
            if (doA) {
                oA[dt] = __builtin_amdgcn_mfma_f32_16x16x32_bf16(pfA0, v0, oA[dt], 0, 0, 0);
                oA[dt] = __builtin_amdgcn_mfma_f32_16x16x32_bf16(pfA1, v1, oA[dt], 0, 0, 0);
            }
            oB[dt] = __builtin_amdgcn_mfma_f32_16x16x32_bf16(pfB0, v0, oB[dt], 0, 0, 0);
            oB[dt] = __builtin_amdgcn_mfma_f32_16x16x32_bf16(pfB1, v1, oB[dt], 0, 0, 0);
        }
        // denominator: l[row] = sum_k P[row][k] via ones-MFMA (lands in C-layout)
        if (doA) {
            lacA = __builtin_amdgcn_mfma_f32_16x16x32_bf16(pfA0, bones, lacA, 0, 0, 0);
            lacA = __builtin_amdgcn_mfma_f32_16x16x32_bf16(pfA1, bones, lacA, 0, 0, 0);
        }
        lacB = __builtin_amdgcn_mfma_f32_16x16x32_bf16(pfB0, bones, lacB, 0, 0, 0);
        lacB = __builtin_amdgcn_mfma_f32_16x16x32_bf16(pfB1, bones, lacB, 0, 0, 0);
        __builtin_amdgcn_s_setprio(0);
    };

    // ---- single-barrier double-buffered pipeline ----
    const int nr = (jend >> 1) + 1;      // block-uniform round count
    ISSUE(0);
    WAITV0();
    WRITE(0);
    LBAR();
    for (int t = 0; t < nr; ++t) {
        const bool more = (t + 1 < nr);
        if (more) ISSUE(t + 1);          // loads fly during COMPUTE
        COMPUTE(2 * t + half, t & 1);
        if (more) {
            WAITV0();                    // staged data arrived
            WRITE((t + 1) & 1);          // other buffer: nobody reads it (ledger)
        }
        LBAR();                          // one barrier per round
    }

    // combine halves: fixed m_hat => partials add directly (no rescale).
    __syncthreads();
    if (half) {
        float* cb = &sm.u.comb[w4][lane][0];
        #pragma unroll
        for (int dt = 0; dt < 4; ++dt)
            #pragma unroll
            for (int r = 0; r < 4; ++r) {
                cb[dt * 4 + r]      = oA[dt][r];
                cb[16 + dt * 4 + r] = oB[dt][r];
            }
        #pragma unroll
        for (int r = 0; r < 4; ++r) { cb[32 + r] = lacA[r]; cb[36 + r] = lacB[r]; }
    }
    __syncthreads();
    if (half) return;

    {
        const float* cb = &sm.u.comb[w4][lane][0];
        #pragma unroll
        for (int dt = 0; dt < 4; ++dt)
            #pragma unroll
            for (int r = 0; r < 4; ++r) {
                oA[dt][r] += cb[dt * 4 + r];
                oB[dt][r] += cb[16 + dt * 4 + r];
            }
        #pragma unroll
        for (int r = 0; r < 4; ++r) { lacA[r] += cb[32 + r]; lacB[r] += cb[36 + r]; }
    }

    // invert: lac is ALREADY C-layout (lane holds l[quad*4+r]) -> no shfl gather
    float irA[4], irB[4];
    #pragma unroll
    for (int r = 0; r < 4; ++r) { irA[r] = 1.f / lacA[r]; irB[r] = 1.f / lacB[r]; }

    // epilogue: normalize and write
    const int h = bh & 15, b = bh >> 4;
    #pragma unroll
    for (int dt = 0; dt < 4; ++dt)
        #pragma unroll
        for (int r = 0; r < 4; ++r) {
            const int rowA = qA * 64 + w4 * 16 + quad * 4 + r;
            const int rowB = qB * 64 + w4 * 16 + quad * 4 + r;
            const int col = h * 64 + dt * 16 + l16;
            Z[((size_t)b * T_SEQ + rowA) * D_MODEL + col] = f2bf(oA[dt][r] * irA[r]);
            Z[((size_t)b * T_SEQ + rowB) * D_MODEL + col] = f2bf(oB[dt][r] * irB[r]);
        }
}

// ---------------- launcher ----------------
extern "C" void kernel_launch(void* const* d_in, const int* in_sizes, int n_in,
                              void* d_out, int out_size, void* d_ws, size_t ws_size,
                              hipStream_t stream) {
    const float* x    = (const float*)d_in[0];
    const float* cosp = (const float*)d_in[1];
    const float* sinp = (const float*)d_in[2];
    const float* Wq   = (const float*)d_in[3];
    const float* Wk   = (const float*)d_in[4];
    const float* Wv   = (const float*)d_in[5];
    const float* Wo   = (const float*)d_in[6];

    char* w = (char*)d_ws;
    unsigned short* xb  = (unsigned short*)w; w += (size_t)M_TOT * D_MODEL * 2;    // 8 MB
    unsigned short* wt  = (unsigned short*)w; w += (size_t)4 * D_MODEL * D_MODEL * 2; // 8 MB (q,k,v,o)
    unsigned short* Qb  = (unsigned short*)w; w += (size_t)M_TOT * D_MODEL * 2;    // 8 MB
    unsigned short* Kb  = (unsigned short*)w; w += (size_t)M_TOT * D_MODEL * 2;
    unsigned short* Vtb = (unsigned short*)w; w += (size_t)M_TOT * D_MODEL * 2;    // [bh][d][t]
    unsigned short* Zb  = (unsigned short*)w; w += (size_t)M_TOT * D_MODEL * 2;
    float*          Ks  = (float*)w;          w += 32 * 64 * sizeof(float);        // Ks[bh][64]

    // prep: z<4 transpose W's, z>=4 convert x (fused, one launch)
    prep_kernel<<<dim3(16, 16, 20), 256, 0, stream>>>(x, xb, Wq, Wk, Wv, Wo, wt);

    // QKV: 128x64 blocks, grid 1536 = exactly 2 rounds at 3 blocks/CU resident
    qkv_kernel<<<dim3(32, 16, 3), 256, 0, stream>>>(xb, wt, Qb, cosp, sinp, Ks);

    // 512-thr blocks (8 waves), grid 512 = 2 blocks/CU, double-buffered staging
    attn_kernel<<<dim3(16, 32), 512, 0, stream>>>(Qb, Kb, Vtb, Ks, Zb);

    // out projection -> fp32 d_out (MI=2: 48KB LDS, 512 blocks = 3 blocks/CU capacity)
    gemm_kernel<2><<<dim3(M_TOT / 64, D_MODEL / 128), 256, 0, stream>>>(
        Zb, wt + (size_t)3 * D_MODEL * D_MODEL, (float*)d_out);
}

// Round 15
// 202.498 us; speedup vs baseline: 1.0353x; 1.0353x over previous
//
#include <hip/hip_runtime.h>

typedef __attribute__((ext_vector_type(4))) float f32x4;
typedef __attribute__((ext_vector_type(8))) short short8;
typedef __attribute__((ext_vector_type(8))) unsigned short u16x8;
typedef __attribute__((ext_vector_type(4))) unsigned short u16x4;
typedef __attribute__((ext_vector_type(2))) unsigned int u32x2;

#define D_MODEL 1024
#define NHEADS 16
#define T_SEQ 2048
#define M_TOT 4096   // B*T

__device__ __forceinline__ unsigned short f2bf(float f) {
    union { float f; unsigned int u; } v; v.f = f;
    return (unsigned short)((v.u + 0x7fffu + ((v.u >> 16) & 1u)) >> 16);
}
__device__ __forceinline__ float bf2f(unsigned short b) {
    union { unsigned int u; float f; } v; v.u = ((unsigned int)b) << 16;
    return v.f;
}
// packed f32x2 -> bf16x2 (low = src0, high = src1)
__device__ __forceinline__ unsigned int cvtpk_bf16(float lo, float hi) {
    unsigned int r;
    asm("v_cvt_pk_bf16_f32 %0, %1, %2" : "=v"(r) : "v"(lo), "v"(hi));
    return r;
}

// volatile asm load: issue point pinned (cannot be sunk/hoisted by the compiler)
#define GLD0(dst, addr) \
    asm volatile("global_load_dwordx4 %0, %1, off" : "=v"(dst) : "v"(addr) : "memory")
// wait all asm/glds loads done, and fence the scheduler (guide rule #18)
#define WAITV0() do { asm volatile("s_waitcnt vmcnt(0)" ::: "memory"); \
                      __builtin_amdgcn_sched_barrier(0); } while (0)
// raw barrier: drain LDS only (NOT vmcnt -> in-flight prefetch survives the barrier)
#define LBAR() do { asm volatile("s_waitcnt lgkmcnt(0)" ::: "memory"); \
                    __builtin_amdgcn_s_barrier(); \
                    __builtin_amdgcn_sched_barrier(0); } while (0)

// async global -> LDS, 16B per lane, LDS dest = wave-uniform base + lane*16
#define GLDS16(gp, lp) \
    __builtin_amdgcn_global_load_lds((const __attribute__((address_space(1))) void*)(gp), \
                                     (__attribute__((address_space(3))) void*)(lp), 16, 0, 0)

// ---------------- prep: convert x fp32->bf16  +  4x W transpose->bf16 (one launch) ----------------
__global__ __launch_bounds__(256) void prep_kernel(const float* __restrict__ X,
                                                   unsigned short* __restrict__ Xb,
                                                   const float* __restrict__ W0,
                                                   const float* __restrict__ W1,
                                                   const float* __restrict__ W2,
                                                   const float* __restrict__ W3,
                                                   unsigned short* __restrict__ Wt0) {
    __shared__ float tile[64][65];
    const int z = blockIdx.z;
    if (z >= 4) {
        // convert: 16 z-slices x 256 blocks x 256 thr x 4 floats = 4096*1024
        const int blk = (z - 4) * 256 + blockIdx.y * 16 + blockIdx.x;
        const int i = (blk * 256 + threadIdx.x) * 4;
        const float4 v = *(const float4*)(X + i);
        u16x4 r;
        r.x = f2bf(v.x); r.y = f2bf(v.y); r.z = f2bf(v.z); r.w = f2bf(v.w);
        *(u16x4*)(Xb + i) = r;
        return;
    }
    const float* W = (z == 0) ? W0 : (z == 1) ? W1 : (z == 2) ? W2 : W3;
    unsigned short* Wt = Wt0 + (size_t)z * D_MODEL * D_MODEL;
    const int n0 = blockIdx.x * 64, k0 = blockIdx.y * 64;
    for (int i = threadIdx.x; i < 4096; i += 256) {
        const int r = i >> 6, c = i & 63;
        tile[r][c] = W[(size_t)(k0 + r) * D_MODEL + n0 + c];
    }
    __syncthreads();
    for (int i = threadIdx.x; i < 4096; i += 256) {
        const int r = i >> 6, c = i & 63;  // r: n-local, c: k-local
        Wt[(size_t)(n0 + r) * D_MODEL + k0 + c] = f2bf(tile[c][r]);
    }
}

// ---------------- GEMM: C = A[M][1024] @ W, Wt[n][k] pre-transposed ----------------
// R11 structure (glds + BK=64 + pre-swizzled global source; conflict-free frag reads).
// Measured rules: this single-barrier double-buffered loop REQUIRES >=2 resident
// blocks/CU (R12: 1/CU -> 78.5us); TN=64 QKV split regresses (R14: A-panel staging
// traffic doubles). R13 config = measured best (203.8us): QKV z-in-grid 768 blocks
// @2/CU, out-proj MI=2 512 blocks.
// kmax fused in z==1 epilogue (norm from fp32 acc; RoPE is norm-preserving).
#define TN_G 128
#define BK_G 64

template<int MI, int OUTMODE>
__global__ __launch_bounds__(256) void gemm_kernel(
    const unsigned short* __restrict__ A,
    const unsigned short* __restrict__ Bt0,
    void* __restrict__ Cout0,
    const float* __restrict__ cosp,
    const float* __restrict__ sinp,
    float* __restrict__ Kmax)
{
    constexpr int TMc = MI * 32;
    constexpr int NCHA = TMc / 8;           // A chunks (8 rows x 128B = 1KB each)
    constexpr int NCHB = TN_G / 8;          // B chunks
    __shared__ unsigned short sA[2][TMc * 64];
    __shared__ unsigned short sB[2][TN_G * 64];

    const int tid = threadIdx.x;
    const int wid = tid >> 6;
    const int lane = tid & 63;
    const int quad = lane >> 4;
    const int l16 = lane & 15;
    const int wm = wid >> 1, wn = wid & 1;
    const int m0 = blockIdx.x * TMc, n0 = blockIdx.y * TN_G;
    const int z = blockIdx.z;
    const unsigned short* Bt = Bt0 + (size_t)z * D_MODEL * D_MODEL;
    const int r8 = lane >> 3;               // staging row within chunk (0..7)
    const int c8 = lane & 7;                // staging 16B slot (0..7)
    const int cswz = (c8 ^ r8) * 8;         // swizzled global u16 col offset
    const int rx = l16 & 7;                 // frag-read row XOR

    f32x4 acc[MI][4] = {};

    auto STAGE = [&](int b, int k0) {
        for (int ch = wid; ch < NCHA + NCHB; ch += 4) {
            if (ch < NCHA)
                GLDS16(A + (size_t)(m0 + ch * 8 + r8) * D_MODEL + k0 + cswz,
                       &sA[b][ch * 512]);
            else
                GLDS16(Bt + (size_t)(n0 + (ch - NCHA) * 8 + r8) * D_MODEL + k0 + cswz,
                       &sB[b][(ch - NCHA) * 512]);
        }
    };
    auto COMPUTE = [&](int b) {
        #pragma unroll
        for (int ks = 0; ks < 2; ++ks) {
            const int sx = ((ks * 4 + quad) ^ rx) * 8;
            short8 af[MI], bf[4];
            #pragma unroll
            for (int i = 0; i < MI; ++i)
                af[i] = *(const short8*)&sA[b][(wm * (MI * 16) + i * 16 + l16) * 64 + sx];
            #pragma unroll
            for (int i = 0; i < 4; ++i)
                bf[i] = *(const short8*)&sB[b][(wn * 64 + i * 16 + l16) * 64 + sx];
            #pragma unroll
            for (int mi = 0; mi < MI; ++mi)
                #pragma unroll
                for (int ni = 0; ni < 4; ++ni)
                    acc[mi][ni] = __builtin_amdgcn_mfma_f32_16x16x32_bf16(af[mi], bf[ni], acc[mi][ni], 0, 0, 0);
        }
    };

    // single-barrier double-buffered K loop (16 steps of BK=64)
    STAGE(0, 0);
    WAITV0();
    LBAR();
    for (int kk = 0; kk < D_MODEL / BK_G; ++kk) {
        if (kk + 1 < D_MODEL / BK_G) STAGE((kk + 1) & 1, (kk + 1) * BK_G);
        COMPUTE(kk & 1);
        WAITV0();          // own glds drained (flew during COMPUTE)
        LBAR();            // all stages visible; my frag reads done
    }

    if constexpr (OUTMODE == 0) {
        float* C = (float*)Cout0;
        #pragma unroll
        for (int mi = 0; mi < MI; ++mi) {
            const int mb = m0 + wm * (MI * 16) + mi * 16 + quad * 4;
            #pragma unroll
            for (int ni = 0; ni < 4; ++ni) {
                const int n = n0 + wn * 64 + ni * 16 + l16;
                #pragma unroll
                for (int r = 0; r < 4; ++r)
                    C[(size_t)(mb + r) * D_MODEL + n] = acc[mi][ni][r];
            }
        }
    } else {
        unsigned short* O = (unsigned short*)Cout0 + (size_t)z * M_TOT * D_MODEL;
        const int h = (n0 + wn * 64) >> 6;   // each wave's 64 cols = exactly one head
        if (z == 2) {
            // V: write transposed Vt[bh][d][t], packed u16x4 over 4 consecutive t
            #pragma unroll
            for (int mi = 0; mi < MI; ++mi) {
                const int mb = m0 + wm * (MI * 16) + mi * 16 + quad * 4;
                const int b = mb >> 11, t = mb & (T_SEQ - 1);
                #pragma unroll
                for (int ni = 0; ni < 4; ++ni) {
                    const int d = ni * 16 + l16;
                    u16x4 pk;
                    #pragma unroll
                    for (int r = 0; r < 4; ++r) pk[r] = f2bf(acc[mi][ni][r]);
                    *(u16x4*)(O + ((size_t)(b * NHEADS + h) * 64 + d) * T_SEQ + t) = pk;
                }
            }
        } else {
            if (z == 1) {
                // fused kmax: max ||k_row|| over this wave's 64 rows (one head)
                float mx = 0.f;
                #pragma unroll
                for (int mi = 0; mi < MI; ++mi)
                    #pragma unroll
                    for (int r = 0; r < 4; ++r) {
                        float s = 0.f;
                        #pragma unroll
                        for (int ni = 0; ni < 4; ++ni) s += acc[mi][ni][r] * acc[mi][ni][r];
                        s += __shfl_xor(s, 1); s += __shfl_xor(s, 2);
                        s += __shfl_xor(s, 4); s += __shfl_xor(s, 8);
                        mx = fmaxf(mx, s);
                    }
                mx = fmaxf(mx, __shfl_xor(mx, 16));
                mx = fmaxf(mx, __shfl_xor(mx, 32));
                if (lane == 0) {
                    const int b = m0 >> 11;
                    const int slot = ((m0 >> 7) & 15) * 2 + wm;
                    Kmax[(size_t)(b * NHEADS + h) * 32 + slot] = __builtin_sqrtf(mx);
                }
            }
            const float qs = (z == 0) ? 0.125f : 1.0f;   // fold 1/sqrt(64) into Q (exact in bf16)
            #pragma unroll
            for (int mi = 0; mi < MI; ++mi) {
                #pragma unroll
                for (int r = 0; r < 4; ++r) {
                    const int m = m0 + wm * (MI * 16) + mi * 16 + quad * 4 + r;
                    const int b = m >> 11, t = m & (T_SEQ - 1);
                    const size_t rowoff = ((size_t)(b * NHEADS + h) * T_SEQ + t) * 64;
                    #pragma unroll
                    for (int ni = 0; ni < 2; ++ni) {
                        const int d = ni * 16 + l16;           // 0..31
                        const float c = cosp[t * 32 + d], s = sinp[t * 32 + d];
                        const float x1 = acc[mi][ni][r], x2 = acc[mi][ni + 2][r];
                        O[rowoff + d]      = f2bf((x1 * c - x2 * s) * qs);
                        O[rowoff + d + 32] = f2bf((x1 * s + x2 * c) * qs);
                    }
                }
            }
        }
    }
}

// ---------------- flash attention (causal): SINGLE-PASS, Cauchy-Schwarz max bound ----------------
// m_hat = ||q_row|| * max_j ||k_j|| >= max s (softmax shift-invariant -> exact math).
// p = exp2(s*log2e - m_hat*log2e) <= ~1 structurally.
// R9/R13 structure (validated 57.5-59.6us): cooperative LDS staging, kv double
// buffer, one barrier/round, XOR-swizzled P, setprio around MFMA, l via ONES-MFMA
// (B-frag = splat bf16 1.0; l lands in C-layout, sums the exact rounded-bf16 p
// the PV numerator consumes).
#define LOG2E 1.44269504f

struct AttnSmem {
    union {
        unsigned short kv[2][4][4096];  // [buf][K0,V0,K1,V1][row*64 + swz-slot*8] = 65536 B
        float comb[4][64][40];          // 40960 B: half=1 partials (O 32 + lacA 4 + lacB 4)
    } u;
    unsigned short P[8][16 * 64];       // per-wave P tile, XOR-swizzled rows = 16384 B
};                                      // total 81920 B

__global__ __launch_bounds__(512, 2) void attn_kernel(
    const unsigned short* __restrict__ Q,    // [bh][t][64] bf16, RoPE'd, pre-scaled 0.125
    const unsigned short* __restrict__ Kg,   // [bh][t][64] bf16, RoPE'd
    const unsigned short* __restrict__ Vt,   // [bh][d][t]  bf16 (transposed)
    const float* __restrict__ Kseg,          // [bh][32] segment maxes of ||k||
    unsigned short* __restrict__ Z)          // [m][h*64+d] bf16
{
    __shared__ AttnSmem sm;

    const int tid = threadIdx.x;
    const int wid = tid >> 6;        // 0..7
    const int w4 = wid & 3;          // row-slice within q-tile
    const int half = wid >> 2;       // 0: even j, 1: odd j
    const int lane = tid & 63;
    const int quad = lane >> 4;
    const int l16 = lane & 15;
    const int srow = tid >> 3;       // staging row 0..63
    const int sslot = tid & 7;       // staging 16B slot
    const int wslot = sslot ^ (srow & 7);          // swizzled slot
    const int sxK = (quad ^ (l16 & 7)) << 3;       // kv frag-read swizzled elem offset
    const int ph8 = (l16 & 7) << 3;                // P row XOR (u16 units)

    // XCD-locality remap (bijective): flat%8 selects XCD; each XCD owns 4 whole bh.
    const int flat = blockIdx.x + 16 * blockIdx.y;     // 0..511
    const int xcd = flat & 7, idx = flat >> 3;         // idx 0..63
    const int bh = xcd * 4 + (idx & 3);                // 0..31
    const int x = idx >> 2;                            // 0..15

    const int qA = x, qB = 31 - x;       // paired q-tiles: 33 tiles/block, constant
    const int jend = 31 - x;             // kv tiles 0..jend cover both

    const unsigned short* Qp = Q + (size_t)bh * T_SEQ * 64;
    const unsigned short* Kp = Kg + (size_t)bh * T_SEQ * 64;
    const unsigned short* Vp = Vt + (size_t)bh * 64 * T_SEQ;

    // Q frags (B-operand in swapped QK): row = qt*64 + w4*16 + l16, k = ks*32 + quad*8
    short8 aqA[2], aqB[2];
    {
        const unsigned short* qr = Qp + (size_t)(qA * 64 + w4 * 16 + l16) * 64 + quad * 8;
        aqA[0] = *(const short8*)(qr);
        aqA[1] = *(const short8*)(qr + 32);
        qr = Qp + (size_t)(qB * 64 + w4 * 16 + l16) * 64 + quad * 8;
        aqB[0] = *(const short8*)(qr);
        aqB[1] = *(const short8*)(qr + 32);
    }

    // max bound: per-lane scalar for q-row l16 (swapped layout: lane = q-row)
    float kmx = 0.f;
    #pragma unroll
    for (int i = 0; i < 32; ++i) kmx = fmaxf(kmx, Kseg[bh * 32 + i]);

    float mQA, mQB;
    {
        float nqA = 0.f, nqB = 0.f;
        #pragma unroll
        for (int i = 0; i < 2; ++i)
            #pragma unroll
            for (int e = 0; e < 8; ++e) {
                const float fa = bf2f((unsigned short)aqA[i][e]);
                const float fb = bf2f((unsigned short)aqB[i][e]);
                nqA += fa * fa; nqB += fb * fb;
            }
        nqA += __shfl_xor(nqA, 16); nqA += __shfl_xor(nqA, 32);
        nqB += __shfl_xor(nqB, 16); nqB += __shfl_xor(nqB, 32);
        mQA = __builtin_sqrtf(nqA) * kmx * LOG2E;
        mQB = __builtin_sqrtf(nqB) * kmx * LOG2E;
    }

    // ones B-frag for the denominator MFMA (bf16 1.0 = 0x3F80)
    short8 bones;
    #pragma unroll
    for (int e = 0; e < 8; ++e) bones[e] = (short)0x3F80;

    auto tile_pack = [&](f32x4 (&s)[4], float mQ, bool msk, unsigned short* Pw) {
        if (msk) {
            #pragma unroll
            for (int nt = 0; nt < 4; ++nt)
                #pragma unroll
                for (int r = 0; r < 4; ++r)
                    if (nt * 16 + quad * 4 + r > w4 * 16 + l16) s[nt][r] = -1e30f;
        }
        #pragma unroll
        for (int nt = 0; nt < 4; ++nt) {
            const float p0 = __builtin_exp2f(s[nt][0] * LOG2E - mQ);
            const float p1 = __builtin_exp2f(s[nt][1] * LOG2E - mQ);
            const float p2 = __builtin_exp2f(s[nt][2] * LOG2E - mQ);
            const float p3 = __builtin_exp2f(s[nt][3] * LOG2E - mQ);
            const unsigned int w0 = cvtpk_bf16(p0, p1);
            const unsigned int w1 = cvtpk_bf16(p2, p3);
            *(u32x2*)&Pw[l16 * 64 + ((nt * 16 + quad * 4) ^ ph8)] = (u32x2){w0, w1};
        }
    };

    f32x4 oA[4] = {}, oB[4] = {};
    f32x4 lacA = {}, lacB = {};          // denominator accumulators (C-layout rows)
    unsigned short* Pw = &sm.P[wid][0];

    short8 stg[4];
    auto ISSUE = [&](int t) {   // 4 contiguous 16B loads per thread (pinned issue)
        const int j0 = 2 * t, j1 = j0 + 1;
        GLD0(stg[0], Kp + (size_t)j0 * 4096 + tid * 8);
        GLD0(stg[1], Vp + (size_t)srow * 2048 + j0 * 64 + sslot * 8);
        GLD0(stg[2], Kp + (size_t)j1 * 4096 + tid * 8);
        GLD0(stg[3], Vp + (size_t)srow * 2048 + j1 * 64 + sslot * 8);
    };
    auto WRITE = [&](int b) {   // swizzled LDS store of the staged 64B
        const int dst = srow * 64 + (wslot << 3);
        *(short8*)&sm.u.kv[b][0][dst] = stg[0];
        *(short8*)&sm.u.kv[b][1][dst] = stg[1];
        *(short8*)&sm.u.kv[b][2][dst] = stg[2];
        *(short8*)&sm.u.kv[b][3][dst] = stg[3];
    };

    auto COMPUTE = [&](int j, int b) {
        if (j > jend) return;            // last round: odd half may be inactive
        const bool doA = (j <= x);
        const unsigned short* sKb = &sm.u.kv[b][half * 2][0];
        const unsigned short* sVb = &sm.u.kv[b][half * 2 + 1][0];
        f32x4 sA[4] = {}, sB[4] = {};
        __builtin_amdgcn_s_setprio(1);
        #pragma unroll
        for (int nt = 0; nt < 4; ++nt) {
            const int rb = (nt * 16 + l16) * 64;
            const short8 k0 = *(const short8*)&sKb[rb + sxK];
            const short8 k1 = *(const short8*)&sKb[rb + (sxK ^ 32)];
            if (doA) {
                sA[nt] = __builtin_amdgcn_mfma_f32_16x16x32_bf16(k0, aqA[0], sA[nt], 0, 0, 0);
                sA[nt] = __builtin_amdgcn_mfma_f32_16x16x32_bf16(k1, aqA[1], sA[nt], 0, 0, 0);
            }
            sB[nt] = __builtin_amdgcn_mfma_f32_16x16x32_bf16(k0, aqB[0], sB[nt], 0, 0, 0);
            sB[nt] = __builtin_amdgcn_mfma_f32_16x16x32_bf16(k1, aqB[1], sB[nt], 0, 0, 0);
        }
        __builtin_amdgcn_s_setprio(0);
        short8 pfA0 = {}, pfA1 = {};
        if (doA) {
            tile_pack(sA, mQA, j == x, Pw);
            asm volatile("s_waitcnt lgkmcnt(0)" ::: "memory");
            pfA0 = *(const short8*)&Pw[l16 * 64 + ((quad * 8) ^ ph8)];
            pfA1 = *(const short8*)&Pw[l16 * 64 + ((32 + quad * 8) ^ ph8)];
        }
        tile_pack(sB, mQB, j == jend, Pw);
        asm volatile("s_waitcnt lgkmcnt(0)" ::: "memory");
        const short8 pfB0 = *(const short8*)&Pw[l16 * 64 + ((quad * 8) ^ ph8)];
        const short8 pfB1 = *(const short8*)&Pw[l16 * 64 + ((32 + quad * 8) ^ ph8)];
        __builtin_amdgcn_s_setprio(1);
        #pragma unroll
        for (int dt = 0; dt < 4; ++dt) {
            const int rb = (dt * 16 + l16) * 64;
            const short8 v0 = *(const short8*)&sVb[rb + sxK];
            const short8 v1 = *(const short8*)&sVb[rb + (sxK ^ 32)];
            if (doA) {
                oA[dt] = __builtin_amdgcn_mfma_f32_16x16x32_bf16(pfA0, v0, oA[dt], 0, 0, 0);
                oA[dt] = __builtin_amdgcn_mfma_f32_16x16x32_bf16(pfA1, v1, oA[dt], 0, 0, 0);
            }
            oB[dt] = __builtin_amdgcn_mfma_f32_16x16x32_bf16(pfB0, v0, oB[dt], 0, 0, 0);
            oB[dt] = __builtin_amdgcn_mfma_f32_16x16x32_bf16(pfB1, v1, oB[dt], 0, 0, 0);
        }
        // denominator: l[row] = sum_k P[row][k] via ones-MFMA (lands in C-layout)
        if (doA) {
            lacA = __builtin_amdgcn_mfma_f32_16x16x32_bf16(pfA0, bones, lacA, 0, 0, 0);
            lacA = __builtin_amdgcn_mfma_f32_16x16x32_bf16(pfA1, bones, lacA, 0, 0, 0);
        }
        lacB = __builtin_amdgcn_mfma_f32_16x16x32_bf16(pfB0, bones, lacB, 0, 0, 0);
        lacB = __builtin_amdgcn_mfma_f32_16x16x32_bf16(pfB1, bones, lacB, 0, 0, 0);
        __builtin_amdgcn_s_setprio(0);
    };

    // ---- single-barrier double-buffered pipeline ----
    const int nr = (jend >> 1) + 1;      // block-uniform round count
    ISSUE(0);
    WAITV0();
    WRITE(0);
    LBAR();
    for (int t = 0; t < nr; ++t) {
        const bool more = (t + 1 < nr);
        if (more) ISSUE(t + 1);          // loads fly during COMPUTE
        COMPUTE(2 * t + half, t & 1);
        if (more) {
            WAITV0();                    // staged data arrived
            WRITE((t + 1) & 1);          // other buffer: nobody reads it (ledger)
        }
        LBAR();                          // one barrier per round
    }

    // combine halves: fixed m_hat => partials add directly (no rescale).
    __syncthreads();
    if (half) {
        float* cb = &sm.u.comb[w4][lane][0];
        #pragma unroll
        for (int dt = 0; dt < 4; ++dt)
            #pragma unroll
            for (int r = 0; r < 4; ++r) {
                cb[dt * 4 + r]      = oA[dt][r];
                cb[16 + dt * 4 + r] = oB[dt][r];
            }
        #pragma unroll
        for (int r = 0; r < 4; ++r) { cb[32 + r] = lacA[r]; cb[36 + r] = lacB[r]; }
    }
    __syncthreads();
    if (half) return;

    {
        const float* cb = &sm.u.comb[w4][lane][0];
        #pragma unroll
        for (int dt = 0; dt < 4; ++dt)
            #pragma unroll
            for (int r = 0; r < 4; ++r) {
                oA[dt][r] += cb[dt * 4 + r];
                oB[dt][r] += cb[16 + dt * 4 + r];
            }
        #pragma unroll
        for (int r = 0; r < 4; ++r) { lacA[r] += cb[32 + r]; lacB[r] += cb[36 + r]; }
    }

    // invert: lac is ALREADY C-layout (lane holds l[quad*4+r]) -> no shfl gather
    float irA[4], irB[4];
    #pragma unroll
    for (int r = 0; r < 4; ++r) { irA[r] = 1.f / lacA[r]; irB[r] = 1.f / lacB[r]; }

    // epilogue: normalize and write
    const int h = bh & 15, b = bh >> 4;
    #pragma unroll
    for (int dt = 0; dt < 4; ++dt)
        #pragma unroll
        for (int r = 0; r < 4; ++r) {
            const int rowA = qA * 64 + w4 * 16 + quad * 4 + r;
            const int rowB = qB * 64 + w4 * 16 + quad * 4 + r;
            const int col = h * 64 + dt * 16 + l16;
            Z[((size_t)b * T_SEQ + rowA) * D_MODEL + col] = f2bf(oA[dt][r] * irA[r]);
            Z[((size_t)b * T_SEQ + rowB) * D_MODEL + col] = f2bf(oB[dt][r] * irB[r]);
        }
}

// ---------------- launcher ----------------
extern "C" void kernel_launch(void* const* d_in, const int* in_sizes, int n_in,
                              void* d_out, int out_size, void* d_ws, size_t ws_size,
                              hipStream_t stream) {
    const float* x    = (const float*)d_in[0];
    const float* cosp = (const float*)d_in[1];
    const float* sinp = (const float*)d_in[2];
    const float* Wq   = (const float*)d_in[3];
    const float* Wk   = (const float*)d_in[4];
    const float* Wv   = (const float*)d_in[5];
    const float* Wo   = (const float*)d_in[6];

    char* w = (char*)d_ws;
    unsigned short* xb  = (unsigned short*)w; w += (size_t)M_TOT * D_MODEL * 2;    // 8 MB
    unsigned short* wt  = (unsigned short*)w; w += (size_t)4 * D_MODEL * D_MODEL * 2; // 8 MB (q,k,v,o)
    unsigned short* Qb  = (unsigned short*)w; w += (size_t)M_TOT * D_MODEL * 2;    // 8 MB
    unsigned short* Kb  = (unsigned short*)w; w += (size_t)M_TOT * D_MODEL * 2;
    unsigned short* Vtb = (unsigned short*)w; w += (size_t)M_TOT * D_MODEL * 2;    // [bh][d][t]
    unsigned short* Zb  = (unsigned short*)w; w += (size_t)M_TOT * D_MODEL * 2;
    float*          Ks  = (float*)w;          w += 32 * 32 * sizeof(float);        // Ks[bh][32]

    // prep: z<4 transpose W's, z>=4 convert x (fused, one launch)
    prep_kernel<<<dim3(16, 16, 20), 256, 0, stream>>>(x, xb, Wq, Wk, Wv, Wo, wt);

    // fused QKV projection, z-in-grid (768 blocks -> 2 blocks/CU resident);
    // epilogue: z=0 Q(RoPE,*0.125), z=1 K(RoPE + kmax), z=2 V(transposed)
    gemm_kernel<4, 1><<<dim3(M_TOT / 128, D_MODEL / 128, 3), 256, 0, stream>>>(
        xb, wt, (void*)Qb, cosp, sinp, Ks);

    // 512-thr blocks (8 waves), grid 512 = 2 blocks/CU, double-buffered staging
    attn_kernel<<<dim3(16, 32), 512, 0, stream>>>(Qb, Kb, Vtb, Ks, Zb);

    // out projection -> fp32 d_out (MI=2: 48KB LDS, 512 blocks = 3 blocks/CU capacity)
    gemm_kernel<2, 0><<<dim3(M_TOT / 64, D_MODEL / 128, 1), 256, 0, stream>>>(
        Zb, wt + (size_t)3 * D_MODEL * D_MODEL, d_out, nullptr, nullptr, nullptr);
}